// Round 11
// baseline (165.973 us; speedup 1.0000x reference)
//
#include <hip/hip_runtime.h>

#define B_   4
#define T_   2048
#define E_   512
#define D_   512
#define N_   16
#define L_   4
#define TCH  32          // elements per lane — a lane owns 32 contiguous t

typedef __bf16 bf16x8 __attribute__((ext_vector_type(8)));
typedef float  f32x4  __attribute__((ext_vector_type(4)));
typedef float  f32x2  __attribute__((ext_vector_type(2)));
typedef unsigned short us8 __attribute__((ext_vector_type(8)));

__device__ __forceinline__ float us2f(unsigned short u) {
    return __uint_as_float(((unsigned int)u) << 16);
}
__device__ __forceinline__ unsigned short f2us(float f) {
    unsigned int u = __float_as_uint(f);
    unsigned int r = (u + 0x7fffu + ((u >> 16) & 1u)) >> 16;   // RNE
    return (unsigned short)r;
}
__device__ __forceinline__ float ldin(const void* p, int i, unsigned int f) {
    return f ? ((const float*)p)[i] : us2f(((const unsigned short*)p)[i]);
}
__device__ __forceinline__ unsigned int probe_f32(const void* lnfs) {
    return (((const unsigned int*)lnfs)[0] == 0x3F800000u) ? 1u : 0u;
}
__device__ __forceinline__ f32x2 pk_fma(f32x2 a, f32x2 b, f32x2 c) {
    f32x2 d;
    asm("v_pk_fma_f32 %0, %1, %2, %3" : "=v"(d) : "v"(a), "v"(b), "v"(c));
    return d;
}
// masked-row DPP (0x142/0x143): masked lanes must yield 0 for the fma — old=0 form
template<int CTRL, int RM>
__device__ __forceinline__ f32x2 dpp2(f32x2 v) {
    f32x2 r;
    r[0] = __int_as_float(__builtin_amdgcn_update_dpp(0, __float_as_int(v[0]), CTRL, RM, 0xF, true));
    r[1] = __int_as_float(__builtin_amdgcn_update_dpp(0, __float_as_int(v[1]), CTRL, RM, 0xF, true));
    return r;
}
// full-mask DPP: single v_mov_b32_dpp, bound_ctrl zero-fills invalid lanes
template<int CTRL>
__device__ __forceinline__ f32x2 mdpp2(f32x2 v) {
    f32x2 r;
    r[0] = __int_as_float(__builtin_amdgcn_mov_dpp(__float_as_int(v[0]), CTRL, 0xF, 0xF, true));
    r[1] = __int_as_float(__builtin_amdgcn_mov_dpp(__float_as_int(v[1]), CTRL, 0xF, 0xF, true));
    return r;
}

// canonical param block offsets (floats)
#define PA    0
#define PB    32768
#define PC    65536
#define PDT   98304
#define PDSK  100352
#define PLFS  102400
#define PLFB  102912
#define PWF   103424
#define PLES  103936
#define PLEB  104448
#define PWEN  104960
#define PSC   105472   // [0]=b_f0, [1]=b_en
#define PTF   105474   // tf[d] = ln_f0_scale[d]*W_f0[d]  (512)
#define PTE   105986   // te[d] = ln_en_scale[d]*W_en[d]  (512)
#define PS2   106498   // [Cf, Ce, Df, De] h-independent LN sums

#define NB_TEXT 2048
#define NB_PRM  413       // ceil(105474/256)
#define NB_WT   64        // 8x8 tiles of 64x64
#define NB_S4P  128       // L*D*N/256 — precomputed scan params
// +1 trailing block: tf/te tables + LN scalar reduction

// ---------------- prep: text->bf16, params->fp32 P, Wt transpose, S4 precompute, LN precompute ----------------
__global__ __launch_bounds__(256) void prep_kernel(
    const void* X, const void* Win,
    const void* A_log, const void* B_ssm, const void* C_ssm,
    const void* log_dt, const void* D_skip,
    const void* lnfs, const void* lnfb, const void* Wf0,
    const void* lnes, const void* lneb, const void* Wen,
    const void* bf0, const void* ben,
    unsigned short* __restrict__ textc, unsigned short* __restrict__ Wt,
    float* __restrict__ P, float* __restrict__ P2, float* __restrict__ PW) {
    __shared__ float tile[64 * 65];
    unsigned int f = probe_f32(lnfs);
    int bid = blockIdx.x;
    if (bid < NB_TEXT) {
        int i = (bid * 256 + threadIdx.x) * 8;
        if (f) {
            const float* xf = (const float*)X;
            us8 r;
#pragma unroll
            for (int j = 0; j < 8; j++) r[j] = f2us(xf[i + j]);
            *(us8*)(textc + i) = r;
        } else {
            *(us8*)(textc + i) = *(const us8*)((const unsigned short*)X + i);
        }
    } else if (bid < NB_TEXT + NB_PRM) {
        int i = (bid - NB_TEXT) * 256 + threadIdx.x;
        if      (i < PB)     P[i] = ldin(A_log,  i - PA,   f);
        else if (i < PC)     P[i] = ldin(B_ssm,  i - PB,   f);
        else if (i < PDT)    P[i] = ldin(C_ssm,  i - PC,   f);
        else if (i < PDSK)   P[i] = ldin(log_dt, i - PDT,  f);
        else if (i < PLFS)   P[i] = ldin(D_skip, i - PDSK, f);
        else if (i < PLFB)   P[i] = ldin(lnfs,   i - PLFS, f);
        else if (i < PWF)    P[i] = ldin(lnfb,   i - PLFB, f);
        else if (i < PLES)   P[i] = ldin(Wf0,    i - PWF,  f);
        else if (i < PLEB)   P[i] = ldin(lnes,   i - PLES, f);
        else if (i < PWEN)   P[i] = ldin(lneb,   i - PLEB, f);
        else if (i < PSC)    P[i] = ldin(Wen,    i - PWEN, f);
        else if (i == PSC)     P[i] = ldin(bf0, 0, f);
        else if (i == PSC + 1) P[i] = ldin(ben, 0, f);
    } else if (bid < NB_TEXT + NB_PRM + NB_WT) {
        // Wt[d][e] = W_in[e][d]  (bf16 out), 64x64 LDS tile
        int tb = bid - (NB_TEXT + NB_PRM);
        int d0 = (tb >> 3) * 64, e0 = (tb & 7) * 64;
        int r = threadIdx.x >> 6, i = threadIdx.x & 63;
#pragma unroll
        for (int k = 0; k < 16; k++) {
            int e = k * 4 + r;
            tile[e * 65 + i] = ldin(Win, (e0 + e) * D_ + d0 + i, f);
        }
        __syncthreads();
#pragma unroll
        for (int k = 0; k < 16; k++) {
            int dd = k * 4 + r;
            Wt[(size_t)(d0 + dd) * E_ + e0 + i] = f2us(tile[i * 65 + dd]);
        }
    } else if (bid < NB_TEXT + NB_PRM + NB_WT + NB_S4P) {
        // S4 param precompute: i indexes (l,d,n); per (l,d) P2 layout (stride 32):
        //   [Ab16 | CB16]
        // Chunk length 32 (one lane owns 32 t) -> M = Ab^32.
        // PW power table: PW[ld*1024 + k*16 + n] = M^k. s4 only reads k<=32.
        int i = (bid - (NB_TEXT + NB_PRM + NB_WT)) * 256 + threadIdx.x;   // [0, L*D*N)
        int n = i & 15;
        int ld = i >> 4;                       // l*512 + d
        float dt = __expf(ldin(log_dt, ld, f));
        float A  = -__expf(ldin(A_log, i, f));
        float Ab = __expf(dt * A);
        float Bb = (Ab - 1.f) / A * ldin(B_ssm, i, f);
        float l2M = 46.166241308446827f * dt * A;   // log2(Ab^32) = 32*dt*A/ln2
        float M   = exp2f(l2M);                     // M = Ab^32
        int base = ld * 32 + n;
        P2[base]      = Ab;
        P2[base + 16] = Bb * ldin(C_ssm, i, f);     // CB
        float pw = 1.f;
        size_t pb = ((size_t)ld << 10) + n;
#pragma unroll
        for (int k = 0; k < 33; k++) { PW[pb + (k << 4)] = pw; pw *= M; }
    } else {
        // LN precompute — tf/te per-d tables + 4 h-independent scalar sums.
        int tid = threadIdx.x;
        float cf = 0.f, ce = 0.f, df = 0.f, de = 0.f;
#pragma unroll
        for (int k = 0; k < 2; k++) {
            int d = k * 256 + tid;
            float wf = ldin(Wf0, d, f), we = ldin(Wen, d, f);
            float tf = ldin(lnfs, d, f) * wf, te = ldin(lnes, d, f) * we;
            P[PTF + d] = tf;  P[PTE + d] = te;
            cf += tf; ce += te;
            df = fmaf(ldin(lnfb, d, f), wf, df);
            de = fmaf(ldin(lneb, d, f), we, de);
        }
        tile[tid] = cf; tile[256 + tid] = ce; tile[512 + tid] = df; tile[768 + tid] = de;
        __syncthreads();
        for (int s = 128; s >= 1; s >>= 1) {
            if (tid < s) {
                tile[tid]       += tile[tid + s];
                tile[256 + tid] += tile[256 + tid + s];
                tile[512 + tid] += tile[512 + tid + s];
                tile[768 + tid] += tile[768 + tid + s];
            }
            __syncthreads();
        }
        if (tid == 0) {
            P[PS2 + 0] = tile[0];   P[PS2 + 1] = tile[256];
            P[PS2 + 2] = tile[512]; P[PS2 + 3] = tile[768];
        }
    }
}

// ---------------- GEMM: H[b][d][t] = sum_e X[b][t][e]*W_in[e][d] + freq[t][d] + b_in[d] ----------------
// R20: 64x64 tiles, 1024 blocks = 4 blocks/CU. R22: XCD-chunked remap (kept).
__global__ __launch_bounds__(256) void gemm_kernel(const unsigned short* __restrict__ X,
                                                   const unsigned short* __restrict__ Wt,
                                                   const void* __restrict__ freq,
                                                   const void* __restrict__ b_in,
                                                   const void* __restrict__ lnfs,
                                                   float* __restrict__ H) {
    __shared__ unsigned short wlds[64 * 264];
    const unsigned int fl = probe_f32(lnfs);
    const int tid = threadIdx.x;
    const int w  = tid >> 6;
    const int ln = tid & 15;
    const int q  = (tid >> 4) & 3;
    const int lid = blockIdx.x + 8 * (blockIdx.y + 32 * blockIdx.z);
    const int xcd = lid >> 7, wi = lid & 127;
    const int d0 = (wi & 7) * 64;
    const int t0 = ((xcd << 2) + ((wi >> 3) & 3)) * 64;
    const int b  = wi >> 5;

    f32x4 acc[4];
#pragma unroll
    for (int j = 0; j < 4; j++) { acc[j][0]=0.f; acc[j][1]=0.f; acc[j][2]=0.f; acc[j][3]=0.f; }

    const size_t xbase = ((size_t)b * T_ + t0) * E_;

#pragma unroll
    for (int p = 0; p < 2; ++p) {
        if (p) __syncthreads();
#pragma unroll
        for (int it = 0; it < 8; ++it) {
            int flat = it * 256 + tid;
            int d = flat >> 5;
            int e = (flat & 31) << 3;
            bf16x8 v = *(const bf16x8*)(Wt + (size_t)(d0 + d) * E_ + p * 256 + e);
            *(bf16x8*)(wlds + d * 264 + e) = v;
        }
        __syncthreads();
#pragma unroll
        for (int s = 0; s < 8; ++s) {
            const int eo = s * 32 + q * 8;
            bf16x8 bfr[4];
#pragma unroll
            for (int j = 0; j < 4; j++)
                bfr[j] = *(const bf16x8*)(wlds + (j * 16 + ln) * 264 + eo);
            const int t = w * 16 + ln;
            bf16x8 afr = *(const bf16x8*)(X + xbase + (size_t)t * E_ + p * 256 + eo);
#pragma unroll
            for (int j = 0; j < 4; j++)
                acc[j] = __builtin_amdgcn_mfma_f32_16x16x32_bf16(afr, bfr[j], acc[j], 0, 0, 0);
        }
    }
    // epilogue: H[b][d][t] = acc + freq[t][d] + b_in[d], float4 store along t
#pragma unroll
    for (int j = 0; j < 4; j++) {
        int d  = d0 + j * 16 + ln;
        int tb = t0 + w * 16 + q * 4;
        float bi = ldin(b_in, d, fl);
        f32x4 o;
#pragma unroll
        for (int r4 = 0; r4 < 4; r4++)
            o[r4] = acc[j][r4] + ldin(freq, (tb + r4) * D_ + d, fl) + bi;
        *(f32x4*)(H + ((size_t)b * D_ + d) * T_ + tb) = o;
    }
}

// ---------------- fused 4-layer S4 scan: ONE wave = TWO (b,d) rows (same d), TCH=32 ----------------
// R23: per-wave stall is ~80% (VALUBusy 38% / 2 waves) and TLP is capped
// (2048 rows; every split regressed: TCH-split duplicates KS, n-split paid 1M
// bank conflicts). The untried axis is ILP: one wave runs BOTH batches of a
// (d,b-pair) — params (Ab/W/w1/w2/CB/Dsk) shared, only u/state/z duplicate.
// Independent FMA chains double to 16; no barrier, no LDS, no handoff.
// 512 blocks x 128 thr = 1024 waves = 1 wave/SIMD: all hiding is ILP; param
// loads pipeline once per layer (~one L2 trip exposed). VGPR peak ~176 < 256
// cap at launch_bounds(128) — no spill (R15 lesson). Block = 2 waves = all 4
// b's of one d -> ~9KB param footprint/CU, L1-resident.
__global__ __launch_bounds__(128)
void s4_kernel(float* __restrict__ H, const float* __restrict__ P,
               const float* __restrict__ P2, const float* __restrict__ PW) {
    const int w = threadIdx.x >> 6, lane = threadIdx.x & 63;
    const int d = blockIdx.x;                 // block owns one d; wave owns 2 b's
    float* gp0 = H + (size_t)((2 * w)     * D_ + d) * T_ + lane * TCH;
    float* gp1 = H + (size_t)((2 * w + 1) * D_ + d) * T_ + lane * TCH;

    // ---- entry: both rows' 32 floats -> registers (16x f32x4) ----
    float u0[TCH], u1[TCH];
#pragma unroll
    for (int k = 0; k < TCH / 4; k++) {
        f32x4 v0 = *(const f32x4*)(gp0 + k * 4);
        f32x4 v1 = *(const f32x4*)(gp1 + k * 4);
        u0[k*4] = v0[0]; u0[k*4+1] = v0[1]; u0[k*4+2] = v0[2]; u0[k*4+3] = v0[3];
        u1[k*4] = v1[0]; u1[k*4+1] = v1[1]; u1[k*4+2] = v1[2]; u1[k*4+3] = v1[3];
    }

    for (int l = 0; l < L_; ++l) {
        const float* pp  = P2 + (size_t)((l << 9) + d) * 32;
        const float* pwt = PW + ((size_t)((l << 9) + d) << 10);
        // ---- pass1: chunk sums from zero, both rows, shared Ab ----
        f32x2 Ab[8], s0[8], s1[8];
#pragma unroll
        for (int n = 0; n < 8; n++) Ab[n] = *(const f32x2*)(pp + 2 * n);
#pragma unroll
        for (int n = 0; n < 8; n++) { s0[n][0]=0.f; s0[n][1]=0.f; s1[n][0]=0.f; s1[n][1]=0.f; }
#pragma unroll
        for (int j = 0; j < TCH; j++) {
            f32x2 ua; ua[0] = u0[j]; ua[1] = u0[j];
            f32x2 ub; ub[0] = u1[j]; ub[1] = u1[j];
#pragma unroll
            for (int n = 0; n < 8; n++) s0[n] = pk_fma(Ab[n], s0[n], ua);
#pragma unroll
            for (int n = 0; n < 8; n++) s1[n] = pk_fma(Ab[n], s1[n], ub);
        }
        // ---- Kogge-Stone (shared stage weights from PW), both rows ----
        {
            f32x2 W[8];
#pragma unroll
            for (int n = 0; n < 8; n++) W[n] = *(const f32x2*)(pwt + 16 + 2 * n);    // M^1
#pragma unroll
            for (int n = 0; n < 8; n++) s0[n] = pk_fma(W[n], mdpp2<0x111>(s0[n]), s0[n]);
#pragma unroll
            for (int n = 0; n < 8; n++) s1[n] = pk_fma(W[n], mdpp2<0x111>(s1[n]), s1[n]);
#pragma unroll
            for (int n = 0; n < 8; n++) W[n] = *(const f32x2*)(pwt + 32 + 2 * n);    // M^2
#pragma unroll
            for (int n = 0; n < 8; n++) s0[n] = pk_fma(W[n], mdpp2<0x112>(s0[n]), s0[n]);
#pragma unroll
            for (int n = 0; n < 8; n++) s1[n] = pk_fma(W[n], mdpp2<0x112>(s1[n]), s1[n]);
#pragma unroll
            for (int n = 0; n < 8; n++) W[n] = *(const f32x2*)(pwt + 64 + 2 * n);    // M^4
#pragma unroll
            for (int n = 0; n < 8; n++) s0[n] = pk_fma(W[n], mdpp2<0x114>(s0[n]), s0[n]);
#pragma unroll
            for (int n = 0; n < 8; n++) s1[n] = pk_fma(W[n], mdpp2<0x114>(s1[n]), s1[n]);
#pragma unroll
            for (int n = 0; n < 8; n++) W[n] = *(const f32x2*)(pwt + 128 + 2 * n);   // M^8
#pragma unroll
            for (int n = 0; n < 8; n++) s0[n] = pk_fma(W[n], mdpp2<0x118>(s0[n]), s0[n]);
#pragma unroll
            for (int n = 0; n < 8; n++) s1[n] = pk_fma(W[n], mdpp2<0x118>(s1[n]), s1[n]);
        }
        {
            f32x2 w1[8];
            const float* p1 = pwt + (((lane & 15) + 1) << 4);
#pragma unroll
            for (int n = 0; n < 8; n++) w1[n] = *(const f32x2*)(p1 + 2 * n);         // M^((lane&15)+1)
#pragma unroll
            for (int n = 0; n < 8; n++) s0[n] = pk_fma(w1[n], dpp2<0x142, 0xA>(s0[n]), s0[n]);
#pragma unroll
            for (int n = 0; n < 8; n++) s1[n] = pk_fma(w1[n], dpp2<0x142, 0xA>(s1[n]), s1[n]);
        }
        {
            f32x2 w2[8];
            const float* p2_ = pwt + (((lane & 31) + 1) << 4);
#pragma unroll
            for (int n = 0; n < 8; n++) w2[n] = *(const f32x2*)(p2_ + 2 * n);        // M^((lane&31)+1)
#pragma unroll
            for (int n = 0; n < 8; n++) s0[n] = pk_fma(w2[n], dpp2<0x143, 0xC>(s0[n]), s0[n]);
#pragma unroll
            for (int n = 0; n < 8; n++) s1[n] = pk_fma(w2[n], dpp2<0x143, 0xC>(s1[n]), s1[n]);
        }
        // ---- exclusive shift (wave_shr:1, lane0 -> 0), both rows ----
        f32x2 z0[8], z1[8];
#pragma unroll
        for (int n = 0; n < 8; n++) z0[n] = mdpp2<0x138>(s0[n]);
#pragma unroll
        for (int n = 0; n < 8; n++) z1[n] = mdpp2<0x138>(s1[n]);
        // ---- pass2: z' = Ab*z' + u; y = sum(CB*z') + D*u; gelu; residual ----
        float Dsk = P[PDSK + l * D_ + d];
        f32x2 CB[8];
#pragma unroll
        for (int n = 0; n < 8; n++) CB[n] = *(const f32x2*)(pp + 16 + 2 * n);
#pragma unroll
        for (int j = 0; j < TCH; j++) {
            float ua = u0[j], ub = u1[j];
            f32x2 va; va[0] = ua; va[1] = ua;
            f32x2 vb; vb[0] = ub; vb[1] = ub;
#pragma unroll
            for (int n = 0; n < 8; n++) z0[n] = pk_fma(Ab[n], z0[n], va);
#pragma unroll
            for (int n = 0; n < 8; n++) z1[n] = pk_fma(Ab[n], z1[n], vb);
            f32x2 ya0; ya0[0]=0.f; ya0[1]=0.f;  f32x2 yb0; yb0[0]=0.f; yb0[1]=0.f;
            f32x2 ya1; ya1[0]=0.f; ya1[1]=0.f;  f32x2 yb1; yb1[0]=0.f; yb1[1]=0.f;
#pragma unroll
            for (int n = 0; n < 8; n += 2) {
                ya0 = pk_fma(CB[n],     z0[n],     ya0);
                yb0 = pk_fma(CB[n + 1], z0[n + 1], yb0);
                ya1 = pk_fma(CB[n],     z1[n],     ya1);
                yb1 = pk_fma(CB[n + 1], z1[n + 1], yb1);
            }
            f32x2 sa = ya0 + yb0;
            f32x2 sb = ya1 + yb1;
            float y0 = fmaf(Dsk, ua, sa[0] + sa[1]);
            float y1 = fmaf(Dsk, ub, sb[0] + sb[1]);
            // gelu(y) = y / (1 + e^{-2*0.79788456*(y+0.044715 y^3)}); exp2-folded
            float t0 = fmaf(0.044715f, y0 * y0 * y0, y0);
            float t1 = fmaf(0.044715f, y1 * y1 * y1, y1);
            float e0 = exp2f(-2.30220818f * t0);
            float e1 = exp2f(-2.30220818f * t1);
            float r0 = __builtin_amdgcn_rcpf(1.f + e0);
            float r1 = __builtin_amdgcn_rcpf(1.f + e1);
            u0[j] = fmaf(y0, r0, ua);
            u1[j] = fmaf(y1, r1, ub);
        }
    }
    // ---- exit: both rows' registers -> global ----
#pragma unroll
    for (int k = 0; k < TCH / 4; k++) {
        f32x4 v0, v1;
        v0[0]=u0[k*4]; v0[1]=u0[k*4+1]; v0[2]=u0[k*4+2]; v0[3]=u0[k*4+3];
        v1[0]=u1[k*4]; v1[1]=u1[k*4+1]; v1[2]=u1[k*4+2]; v1[3]=u1[k*4+3];
        *(f32x4*)(gp0 + k * 4) = v0;
        *(f32x4*)(gp1 + k * 4) = v1;
    }
}

// ---------------- final: 2x fused layernorm + projection ----------------
// R20/R22 (kept): 256 blocks x 256 threads; 2-way d-split per lane,
// shfl_xor(32) combine; prep-hoisted tf/te tables + PS2 scalars.
__global__ __launch_bounds__(256) void final_kernel(const float* __restrict__ H,
                                                    const float* __restrict__ P,
                                                    void* __restrict__ out,
                                                    const void* __restrict__ lnfs_raw) {
    __shared__ float red[4][4][32];
    unsigned int f = probe_f32(lnfs_raw);
    int tid = threadIdx.x;
    int w = tid >> 6, lane = tid & 63;
    int tq = lane & 31, dp = lane >> 5;
    int tg = blockIdx.x * 32 + tq;
    int b = tg >> 11, t = tg & (T_ - 1);
    float S1 = 0.f, S2 = 0.f, Pf = 0.f, Pe = 0.f;
    const float* hp = H + ((size_t)b * D_) * T_ + t;
#pragma unroll 4
    for (int k = 0; k < 64; k++) {
        int d = w * 128 + 2 * k + dp;
        float hv = hp[(size_t)d * T_];
        float tf = P[PTF + d], te = P[PTE + d];
        S1 += hv; S2 = fmaf(hv, hv, S2);
        Pf = fmaf(hv, tf, Pf); Pe = fmaf(hv, te, Pe);
    }
    S1 += __shfl_xor(S1, 32); S2 += __shfl_xor(S2, 32);
    Pf += __shfl_xor(Pf, 32); Pe += __shfl_xor(Pe, 32);
    if (dp == 0) {
        red[w][0][tq] = S1; red[w][1][tq] = S2; red[w][2][tq] = Pf; red[w][3][tq] = Pe;
    }
    __syncthreads();
    if (tid < 32) {
        float a[4];
#pragma unroll
        for (int k = 0; k < 4; k++)
            a[k] = red[0][k][tid] + red[1][k][tid] + red[2][k][tid] + red[3][k][tid];
        float mu  = a[0] * (1.f / 512.f);
        float var = a[1] * (1.f / 512.f) - mu * mu;
        float r   = rsqrtf(var + 1e-5f);
        float f0  = r * (a[2] - mu * P[PS2 + 0]) + P[PS2 + 2] + P[PSC + 0];
        float en  = r * (a[3] - mu * P[PS2 + 1]) + P[PS2 + 3] + P[PSC + 1];
        int tg2 = blockIdx.x * 32 + tid;
        if (f) {
            ((float*)out)[tg2]           = f0;
            ((float*)out)[B_ * T_ + tg2] = en;
        } else {
            ((unsigned short*)out)[tg2]           = f2us(f0);
            ((unsigned short*)out)[B_ * T_ + tg2] = f2us(en);
        }
    }
}

extern "C" void kernel_launch(void* const* d_in, const int* in_sizes, int n_in,
                              void* d_out, int out_size, void* d_ws, size_t ws_size,
                              hipStream_t stream) {
    (void)in_sizes; (void)n_in; (void)out_size; (void)ws_size;
    float* ws = (float*)d_ws;
    float* P     = ws;                                      // 106,528 slots (106,502 used)
    float* H     = ws + 106528;                             // 4,194,304
    unsigned short* textc = (unsigned short*)(ws + 4300832);// 4,194,304 bf16 (2,097,152 slots)
    unsigned short* Wt    = (unsigned short*)(ws + 6397984);// 262,144 bf16 (131,072 slots)
    float* P2    = ws + 6529056;                            // L*D*32 = 65,536 floats
    float* PW    = ws + 6594592;                            // L*D*64*16 = 2,097,152 floats (M=Ab^32 powers)
    // total: 8,691,744 floats = 34.8 MB

    prep_kernel<<<dim3(NB_TEXT + NB_PRM + NB_WT + NB_S4P + 1), dim3(256), 0, stream>>>(
        d_in[0], d_in[1], d_in[4], d_in[5], d_in[6], d_in[7], d_in[8],
        d_in[9], d_in[10], d_in[11], d_in[13], d_in[14], d_in[15],
        d_in[12], d_in[16], textc, Wt, P, P2, PW);
    gemm_kernel<<<dim3(8, 32, 4), dim3(256), 0, stream>>>(textc, Wt, d_in[3], d_in[2], d_in[9], H);
    s4_kernel<<<dim3(512), dim3(128), 0, stream>>>(H, P, P2, PW);
    final_kernel<<<dim3(256), dim3(256), 0, stream>>>(H, P, d_out, d_in[9]);
}

// Round 12
// 162.207 us; speedup vs baseline: 1.0232x; 1.0232x over previous
//
#include <hip/hip_runtime.h>

#define B_   4
#define T_   2048
#define E_   512
#define D_   512
#define N_   16
#define L_   4
#define TCH  16          // elements per lane — wave owns 2 rows x half a row

typedef __bf16 bf16x8 __attribute__((ext_vector_type(8)));
typedef float  f32x4  __attribute__((ext_vector_type(4)));
typedef float  f32x2  __attribute__((ext_vector_type(2)));
typedef unsigned short us8 __attribute__((ext_vector_type(8)));

__device__ __forceinline__ float us2f(unsigned short u) {
    return __uint_as_float(((unsigned int)u) << 16);
}
__device__ __forceinline__ unsigned short f2us(float f) {
    unsigned int u = __float_as_uint(f);
    unsigned int r = (u + 0x7fffu + ((u >> 16) & 1u)) >> 16;   // RNE
    return (unsigned short)r;
}
__device__ __forceinline__ float ldin(const void* p, int i, unsigned int f) {
    return f ? ((const float*)p)[i] : us2f(((const unsigned short*)p)[i]);
}
__device__ __forceinline__ unsigned int probe_f32(const void* lnfs) {
    return (((const unsigned int*)lnfs)[0] == 0x3F800000u) ? 1u : 0u;
}
__device__ __forceinline__ f32x2 pk_fma(f32x2 a, f32x2 b, f32x2 c) {
    f32x2 d;
    asm("v_pk_fma_f32 %0, %1, %2, %3" : "=v"(d) : "v"(a), "v"(b), "v"(c));
    return d;
}
// masked-row DPP (0x142/0x143): masked lanes must yield 0 for the fma — old=0 form
template<int CTRL, int RM>
__device__ __forceinline__ f32x2 dpp2(f32x2 v) {
    f32x2 r;
    r[0] = __int_as_float(__builtin_amdgcn_update_dpp(0, __float_as_int(v[0]), CTRL, RM, 0xF, true));
    r[1] = __int_as_float(__builtin_amdgcn_update_dpp(0, __float_as_int(v[1]), CTRL, RM, 0xF, true));
    return r;
}
// full-mask DPP: single v_mov_b32_dpp, bound_ctrl zero-fills invalid lanes
template<int CTRL>
__device__ __forceinline__ f32x2 mdpp2(f32x2 v) {
    f32x2 r;
    r[0] = __int_as_float(__builtin_amdgcn_mov_dpp(__float_as_int(v[0]), CTRL, 0xF, 0xF, true));
    r[1] = __int_as_float(__builtin_amdgcn_mov_dpp(__float_as_int(v[1]), CTRL, 0xF, 0xF, true));
    return r;
}

// canonical param block offsets (floats)
#define PA    0
#define PB    32768
#define PC    65536
#define PDT   98304
#define PDSK  100352
#define PLFS  102400
#define PLFB  102912
#define PWF   103424
#define PLES  103936
#define PLEB  104448
#define PWEN  104960
#define PSC   105472   // [0]=b_f0, [1]=b_en
#define PTF   105474   // tf[d] = ln_f0_scale[d]*W_f0[d]  (512)
#define PTE   105986   // te[d] = ln_en_scale[d]*W_en[d]  (512)
#define PS2   106498   // [Cf, Ce, Df, De] h-independent LN sums

#define NB_TEXT 2048
#define NB_PRM  413       // ceil(105474/256)
#define NB_WT   64        // 8x8 tiles of 64x64
#define NB_S4P  128       // L*D*N/256 — precomputed scan params
// +1 trailing block: tf/te tables + LN scalar reduction

// ---------------- prep: text->bf16, params->fp32 P, Wt transpose, S4 precompute, LN precompute ----------------
__global__ __launch_bounds__(256) void prep_kernel(
    const void* X, const void* Win,
    const void* A_log, const void* B_ssm, const void* C_ssm,
    const void* log_dt, const void* D_skip,
    const void* lnfs, const void* lnfb, const void* Wf0,
    const void* lnes, const void* lneb, const void* Wen,
    const void* bf0, const void* ben,
    unsigned short* __restrict__ textc, unsigned short* __restrict__ Wt,
    float* __restrict__ P, float* __restrict__ P2, float* __restrict__ PW) {
    __shared__ float tile[64 * 65];
    unsigned int f = probe_f32(lnfs);
    int bid = blockIdx.x;
    if (bid < NB_TEXT) {
        int i = (bid * 256 + threadIdx.x) * 8;
        if (f) {
            const float* xf = (const float*)X;
            us8 r;
#pragma unroll
            for (int j = 0; j < 8; j++) r[j] = f2us(xf[i + j]);
            *(us8*)(textc + i) = r;
        } else {
            *(us8*)(textc + i) = *(const us8*)((const unsigned short*)X + i);
        }
    } else if (bid < NB_TEXT + NB_PRM) {
        int i = (bid - NB_TEXT) * 256 + threadIdx.x;
        if      (i < PB)     P[i] = ldin(A_log,  i - PA,   f);
        else if (i < PC)     P[i] = ldin(B_ssm,  i - PB,   f);
        else if (i < PDT)    P[i] = ldin(C_ssm,  i - PC,   f);
        else if (i < PDSK)   P[i] = ldin(log_dt, i - PDT,  f);
        else if (i < PLFS)   P[i] = ldin(D_skip, i - PDSK, f);
        else if (i < PLFB)   P[i] = ldin(lnfs,   i - PLFS, f);
        else if (i < PWF)    P[i] = ldin(lnfb,   i - PLFB, f);
        else if (i < PLES)   P[i] = ldin(Wf0,    i - PWF,  f);
        else if (i < PLEB)   P[i] = ldin(lnes,   i - PLES, f);
        else if (i < PWEN)   P[i] = ldin(lneb,   i - PLEB, f);
        else if (i < PSC)    P[i] = ldin(Wen,    i - PWEN, f);
        else if (i == PSC)     P[i] = ldin(bf0, 0, f);
        else if (i == PSC + 1) P[i] = ldin(ben, 0, f);
    } else if (bid < NB_TEXT + NB_PRM + NB_WT) {
        // Wt[d][e] = W_in[e][d]  (bf16 out), 64x64 LDS tile
        int tb = bid - (NB_TEXT + NB_PRM);
        int d0 = (tb >> 3) * 64, e0 = (tb & 7) * 64;
        int r = threadIdx.x >> 6, i = threadIdx.x & 63;
#pragma unroll
        for (int k = 0; k < 16; k++) {
            int e = k * 4 + r;
            tile[e * 65 + i] = ldin(Win, (e0 + e) * D_ + d0 + i, f);
        }
        __syncthreads();
#pragma unroll
        for (int k = 0; k < 16; k++) {
            int dd = k * 4 + r;
            Wt[(size_t)(d0 + dd) * E_ + e0 + i] = f2us(tile[i * 65 + dd]);
        }
    } else if (bid < NB_TEXT + NB_PRM + NB_WT + NB_S4P) {
        // S4 param precompute: i indexes (l,d,n); per (l,d) P2 layout (stride 32):
        //   [Ab16 | CB16]
        // R24: chunk length 16 (wave = 2 rows x half-row) -> M = Ab^16.
        // PW power table: PW[ld*1024 + k*16 + n] = M^k, k = 0..63. Serves KS
        // stage weights (1,2,4,8), w1 (<=16), w2 (<=32) AND the cross-half
        // decay wh = M^lane (<=63) — no exp2 anywhere in s4.
        int i = (bid - (NB_TEXT + NB_PRM + NB_WT)) * 256 + threadIdx.x;   // [0, L*D*N)
        int n = i & 15;
        int ld = i >> 4;                       // l*512 + d
        float dt = __expf(ldin(log_dt, ld, f));
        float A  = -__expf(ldin(A_log, i, f));
        float Ab = __expf(dt * A);
        float Bb = (Ab - 1.f) / A * ldin(B_ssm, i, f);
        float l2M = 23.083120654223414f * dt * A;   // log2(Ab^16) = 16*dt*A/ln2
        float M   = exp2f(l2M);                     // M = Ab^16
        int base = ld * 32 + n;
        P2[base]      = Ab;
        P2[base + 16] = Bb * ldin(C_ssm, i, f);     // CB
        float pw = 1.f;
        size_t pb = ((size_t)ld << 10) + n;
#pragma unroll
        for (int k = 0; k < 64; k++) { PW[pb + (k << 4)] = pw; pw *= M; }
    } else {
        // LN precompute — tf/te per-d tables + 4 h-independent scalar sums.
        int tid = threadIdx.x;
        float cf = 0.f, ce = 0.f, df = 0.f, de = 0.f;
#pragma unroll
        for (int k = 0; k < 2; k++) {
            int d = k * 256 + tid;
            float wf = ldin(Wf0, d, f), we = ldin(Wen, d, f);
            float tf = ldin(lnfs, d, f) * wf, te = ldin(lnes, d, f) * we;
            P[PTF + d] = tf;  P[PTE + d] = te;
            cf += tf; ce += te;
            df = fmaf(ldin(lnfb, d, f), wf, df);
            de = fmaf(ldin(lneb, d, f), we, de);
        }
        tile[tid] = cf; tile[256 + tid] = ce; tile[512 + tid] = df; tile[768 + tid] = de;
        __syncthreads();
        for (int s = 128; s >= 1; s >>= 1) {
            if (tid < s) {
                tile[tid]       += tile[tid + s];
                tile[256 + tid] += tile[256 + tid + s];
                tile[512 + tid] += tile[512 + tid + s];
                tile[768 + tid] += tile[768 + tid + s];
            }
            __syncthreads();
        }
        if (tid == 0) {
            P[PS2 + 0] = tile[0];   P[PS2 + 1] = tile[256];
            P[PS2 + 2] = tile[512]; P[PS2 + 3] = tile[768];
        }
    }
}

// ---------------- GEMM: H[b][d][t] = sum_e X[b][t][e]*W_in[e][d] + freq[t][d] + b_in[d] ----------------
// R20: 64x64 tiles, 1024 blocks = 4 blocks/CU. R22: XCD-chunked remap (kept).
__global__ __launch_bounds__(256) void gemm_kernel(const unsigned short* __restrict__ X,
                                                   const unsigned short* __restrict__ Wt,
                                                   const void* __restrict__ freq,
                                                   const void* __restrict__ b_in,
                                                   const void* __restrict__ lnfs,
                                                   float* __restrict__ H) {
    __shared__ unsigned short wlds[64 * 264];
    const unsigned int fl = probe_f32(lnfs);
    const int tid = threadIdx.x;
    const int w  = tid >> 6;
    const int ln = tid & 15;
    const int q  = (tid >> 4) & 3;
    const int lid = blockIdx.x + 8 * (blockIdx.y + 32 * blockIdx.z);
    const int xcd = lid >> 7, wi = lid & 127;
    const int d0 = (wi & 7) * 64;
    const int t0 = ((xcd << 2) + ((wi >> 3) & 3)) * 64;
    const int b  = wi >> 5;

    f32x4 acc[4];
#pragma unroll
    for (int j = 0; j < 4; j++) { acc[j][0]=0.f; acc[j][1]=0.f; acc[j][2]=0.f; acc[j][3]=0.f; }

    const size_t xbase = ((size_t)b * T_ + t0) * E_;

#pragma unroll
    for (int p = 0; p < 2; ++p) {
        if (p) __syncthreads();
#pragma unroll
        for (int it = 0; it < 8; ++it) {
            int flat = it * 256 + tid;
            int d = flat >> 5;
            int e = (flat & 31) << 3;
            bf16x8 v = *(const bf16x8*)(Wt + (size_t)(d0 + d) * E_ + p * 256 + e);
            *(bf16x8*)(wlds + d * 264 + e) = v;
        }
        __syncthreads();
#pragma unroll
        for (int s = 0; s < 8; ++s) {
            const int eo = s * 32 + q * 8;
            bf16x8 bfr[4];
#pragma unroll
            for (int j = 0; j < 4; j++)
                bfr[j] = *(const bf16x8*)(wlds + (j * 16 + ln) * 264 + eo);
            const int t = w * 16 + ln;
            bf16x8 afr = *(const bf16x8*)(X + xbase + (size_t)t * E_ + p * 256 + eo);
#pragma unroll
            for (int j = 0; j < 4; j++)
                acc[j] = __builtin_amdgcn_mfma_f32_16x16x32_bf16(afr, bfr[j], acc[j], 0, 0, 0);
        }
    }
    // epilogue: H[b][d][t] = acc + freq[t][d] + b_in[d], float4 store along t
#pragma unroll
    for (int j = 0; j < 4; j++) {
        int d  = d0 + j * 16 + ln;
        int tb = t0 + w * 16 + q * 4;
        float bi = ldin(b_in, d, fl);
        f32x4 o;
#pragma unroll
        for (int r4 = 0; r4 < 4; r4++)
            o[r4] = acc[j][r4] + ldin(freq, (tb + r4) * D_ + d, fl) + bi;
        *(f32x4*)(H + ((size_t)b * D_ + d) * T_ + tb) = o;
    }
}

// ---------------- fused 4-layer S4 scan: block = one d; wave = 2 rows x half, TCH=16 ----------------
// R24: the untried cell — amortization (2 rows/wave, R17/R23-proven) x TLP
// (2 waves/SIMD, R14-proven) x same-d L1 param sharing (R19-proven).
// Block 256 thr = 4 waves: wave (h=w&1, rp=w>>1) handles rows {2rp, 2rp+1}
// over t-half h. 512 blocks x 4 waves = 2048 waves = 2/SIMD. Chunk M = Ab^16;
// KS weights/params loaded ONCE per wave, applied to both rows (16 indep
// chains). Cross-half handoff: R14's parity-double-buffered hstate (512 B),
// one barrier/layer; wh = M^lane from PW (no exp2). VGPR peak ~150 < 256
// needed for 2/SIMD; no waves_per_eu attribute (R15 lesson).
__global__ __launch_bounds__(256)
void s4_kernel(float* __restrict__ H, const float* __restrict__ P,
               const float* __restrict__ P2, const float* __restrict__ PW) {
    __shared__ float hstate[2][2][2][16];     // [parity][rp][row-in-pair][n]
    const int w = threadIdx.x >> 6, lane = threadIdx.x & 63;
    const int h = w & 1, rp = w >> 1;
    const int d = blockIdx.x;
    float* gp0 = H + (size_t)((2 * rp)     * D_ + d) * T_ + h * 1024 + lane * TCH;
    float* gp1 = H + (size_t)((2 * rp + 1) * D_ + d) * T_ + h * 1024 + lane * TCH;

    // ---- entry: both rows' 16 floats -> registers (4x f32x4 each) ----
    float u0[TCH], u1[TCH];
#pragma unroll
    for (int k = 0; k < TCH / 4; k++) {
        f32x4 v0 = *(const f32x4*)(gp0 + k * 4);
        f32x4 v1 = *(const f32x4*)(gp1 + k * 4);
        u0[k*4] = v0[0]; u0[k*4+1] = v0[1]; u0[k*4+2] = v0[2]; u0[k*4+3] = v0[3];
        u1[k*4] = v1[0]; u1[k*4+1] = v1[1]; u1[k*4+2] = v1[2]; u1[k*4+3] = v1[3];
    }

    for (int l = 0; l < L_; ++l) {
        const float* pp  = P2 + (size_t)((l << 9) + d) * 32;
        const float* pwt = PW + ((size_t)((l << 9) + d) << 10);
        // ---- pass1: chunk sums from zero, both rows, shared Ab ----
        f32x2 Ab[8], s0[8], s1[8];
#pragma unroll
        for (int n = 0; n < 8; n++) Ab[n] = *(const f32x2*)(pp + 2 * n);
#pragma unroll
        for (int n = 0; n < 8; n++) { s0[n][0]=0.f; s0[n][1]=0.f; s1[n][0]=0.f; s1[n][1]=0.f; }
#pragma unroll
        for (int j = 0; j < TCH; j++) {
            f32x2 ua; ua[0] = u0[j]; ua[1] = u0[j];
            f32x2 ub; ub[0] = u1[j]; ub[1] = u1[j];
#pragma unroll
            for (int n = 0; n < 8; n++) s0[n] = pk_fma(Ab[n], s0[n], ua);
#pragma unroll
            for (int n = 0; n < 8; n++) s1[n] = pk_fma(Ab[n], s1[n], ub);
        }
        // ---- Kogge-Stone across 64 lanes (M = Ab^16, shared weights), both rows ----
        {
            f32x2 W[8];
#pragma unroll
            for (int n = 0; n < 8; n++) W[n] = *(const f32x2*)(pwt + 16 + 2 * n);    // M^1
#pragma unroll
            for (int n = 0; n < 8; n++) s0[n] = pk_fma(W[n], mdpp2<0x111>(s0[n]), s0[n]);
#pragma unroll
            for (int n = 0; n < 8; n++) s1[n] = pk_fma(W[n], mdpp2<0x111>(s1[n]), s1[n]);
#pragma unroll
            for (int n = 0; n < 8; n++) W[n] = *(const f32x2*)(pwt + 32 + 2 * n);    // M^2
#pragma unroll
            for (int n = 0; n < 8; n++) s0[n] = pk_fma(W[n], mdpp2<0x112>(s0[n]), s0[n]);
#pragma unroll
            for (int n = 0; n < 8; n++) s1[n] = pk_fma(W[n], mdpp2<0x112>(s1[n]), s1[n]);
#pragma unroll
            for (int n = 0; n < 8; n++) W[n] = *(const f32x2*)(pwt + 64 + 2 * n);    // M^4
#pragma unroll
            for (int n = 0; n < 8; n++) s0[n] = pk_fma(W[n], mdpp2<0x114>(s0[n]), s0[n]);
#pragma unroll
            for (int n = 0; n < 8; n++) s1[n] = pk_fma(W[n], mdpp2<0x114>(s1[n]), s1[n]);
#pragma unroll
            for (int n = 0; n < 8; n++) W[n] = *(const f32x2*)(pwt + 128 + 2 * n);   // M^8
#pragma unroll
            for (int n = 0; n < 8; n++) s0[n] = pk_fma(W[n], mdpp2<0x118>(s0[n]), s0[n]);
#pragma unroll
            for (int n = 0; n < 8; n++) s1[n] = pk_fma(W[n], mdpp2<0x118>(s1[n]), s1[n]);
        }
        {
            f32x2 w1[8];
            const float* p1 = pwt + (((lane & 15) + 1) << 4);
#pragma unroll
            for (int n = 0; n < 8; n++) w1[n] = *(const f32x2*)(p1 + 2 * n);         // M^((lane&15)+1)
#pragma unroll
            for (int n = 0; n < 8; n++) s0[n] = pk_fma(w1[n], dpp2<0x142, 0xA>(s0[n]), s0[n]);
#pragma unroll
            for (int n = 0; n < 8; n++) s1[n] = pk_fma(w1[n], dpp2<0x142, 0xA>(s1[n]), s1[n]);
        }
        {
            f32x2 w2[8];
            const float* p2_ = pwt + (((lane & 31) + 1) << 4);
#pragma unroll
            for (int n = 0; n < 8; n++) w2[n] = *(const f32x2*)(p2_ + 2 * n);        // M^((lane&31)+1)
#pragma unroll
            for (int n = 0; n < 8; n++) s0[n] = pk_fma(w2[n], dpp2<0x143, 0xC>(s0[n]), s0[n]);
#pragma unroll
            for (int n = 0; n < 8; n++) s1[n] = pk_fma(w2[n], dpp2<0x143, 0xC>(s1[n]), s1[n]);
        }
        // ---- half0 publishes half-final state (inclusive @ lane63), both rows ----
        if (h == 0 && lane == 63) {
#pragma unroll
            for (int n = 0; n < 8; n++) {
                *(f32x2*)(&hstate[l & 1][rp][0][2 * n]) = s0[n];
                *(f32x2*)(&hstate[l & 1][rp][1][2 * n]) = s1[n];
            }
        }
        // ---- exclusive shift = chunk-initial state (wave_shr:1, lane0 -> 0) ----
        f32x2 z0[8], z1[8];
#pragma unroll
        for (int n = 0; n < 8; n++) z0[n] = mdpp2<0x138>(s0[n]);
#pragma unroll
        for (int n = 0; n < 8; n++) z1[n] = mdpp2<0x138>(s1[n]);
        __syncthreads();
        // ---- half1: add decayed carry z += M^lane * h0 (wh from PW, no exp2) ----
        if (h) {
            f32x2 wh[8];
            const float* pl = pwt + (lane << 4);
#pragma unroll
            for (int n = 0; n < 8; n++) wh[n] = *(const f32x2*)(pl + 2 * n);         // M^lane
            const float* hs0 = hstate[l & 1][rp][0];
            const float* hs1 = hstate[l & 1][rp][1];
#pragma unroll
            for (int n = 0; n < 8; n++) {
                f32x2 h0 = *(const f32x2*)(hs0 + 2 * n);
                f32x2 h1 = *(const f32x2*)(hs1 + 2 * n);
                z0[n] = pk_fma(wh[n], h0, z0[n]);
                z1[n] = pk_fma(wh[n], h1, z1[n]);
            }
        }
        // ---- pass2: z' = Ab*z' + u; y = sum(CB*z') + D*u; gelu; residual ----
        float Dsk = P[PDSK + l * D_ + d];
        f32x2 CB[8];
#pragma unroll
        for (int n = 0; n < 8; n++) CB[n] = *(const f32x2*)(pp + 16 + 2 * n);
#pragma unroll
        for (int j = 0; j < TCH; j++) {
            float ua = u0[j], ub = u1[j];
            f32x2 va; va[0] = ua; va[1] = ua;
            f32x2 vb; vb[0] = ub; vb[1] = ub;
#pragma unroll
            for (int n = 0; n < 8; n++) z0[n] = pk_fma(Ab[n], z0[n], va);
#pragma unroll
            for (int n = 0; n < 8; n++) z1[n] = pk_fma(Ab[n], z1[n], vb);
            f32x2 ya0; ya0[0]=0.f; ya0[1]=0.f;  f32x2 yb0; yb0[0]=0.f; yb0[1]=0.f;
            f32x2 ya1; ya1[0]=0.f; ya1[1]=0.f;  f32x2 yb1; yb1[0]=0.f; yb1[1]=0.f;
#pragma unroll
            for (int n = 0; n < 8; n += 2) {
                ya0 = pk_fma(CB[n],     z0[n],     ya0);
                yb0 = pk_fma(CB[n + 1], z0[n + 1], yb0);
                ya1 = pk_fma(CB[n],     z1[n],     ya1);
                yb1 = pk_fma(CB[n + 1], z1[n + 1], yb1);
            }
            f32x2 sa = ya0 + yb0;
            f32x2 sb = ya1 + yb1;
            float y0 = fmaf(Dsk, ua, sa[0] + sa[1]);
            float y1 = fmaf(Dsk, ub, sb[0] + sb[1]);
            // gelu(y) = y / (1 + e^{-2*0.79788456*(y+0.044715 y^3)}); exp2-folded
            float t0 = fmaf(0.044715f, y0 * y0 * y0, y0);
            float t1 = fmaf(0.044715f, y1 * y1 * y1, y1);
            float e0 = exp2f(-2.30220818f * t0);
            float e1 = exp2f(-2.30220818f * t1);
            float r0 = __builtin_amdgcn_rcpf(1.f + e0);
            float r1 = __builtin_amdgcn_rcpf(1.f + e1);
            u0[j] = fmaf(y0, r0, ua);
            u1[j] = fmaf(y1, r1, ub);
        }
        // no second barrier: hstate is parity-double-buffered (R14-proven);
        // next layer's publish targets [(l+1)&1], and the l+1 barrier orders
        // any write to [l&1] at l+2 after all l reads.
    }
    // ---- exit: both rows' registers -> global ----
#pragma unroll
    for (int k = 0; k < TCH / 4; k++) {
        f32x4 v0, v1;
        v0[0]=u0[k*4]; v0[1]=u0[k*4+1]; v0[2]=u0[k*4+2]; v0[3]=u0[k*4+3];
        v1[0]=u1[k*4]; v1[1]=u1[k*4+1]; v1[2]=u1[k*4+2]; v1[3]=u1[k*4+3];
        *(f32x4*)(gp0 + k * 4) = v0;
        *(f32x4*)(gp1 + k * 4) = v1;
    }
}

// ---------------- final: 2x fused layernorm + projection ----------------
// R20/R22 (kept): 256 blocks x 256 threads; 2-way d-split per lane,
// shfl_xor(32) combine; prep-hoisted tf/te tables + PS2 scalars.
__global__ __launch_bounds__(256) void final_kernel(const float* __restrict__ H,
                                                    const float* __restrict__ P,
                                                    void* __restrict__ out,
                                                    const void* __restrict__ lnfs_raw) {
    __shared__ float red[4][4][32];
    unsigned int f = probe_f32(lnfs_raw);
    int tid = threadIdx.x;
    int w = tid >> 6, lane = tid & 63;
    int tq = lane & 31, dp = lane >> 5;
    int tg = blockIdx.x * 32 + tq;
    int b = tg >> 11, t = tg & (T_ - 1);
    float S1 = 0.f, S2 = 0.f, Pf = 0.f, Pe = 0.f;
    const float* hp = H + ((size_t)b * D_) * T_ + t;
#pragma unroll 4
    for (int k = 0; k < 64; k++) {
        int d = w * 128 + 2 * k + dp;
        float hv = hp[(size_t)d * T_];
        float tf = P[PTF + d], te = P[PTE + d];
        S1 += hv; S2 = fmaf(hv, hv, S2);
        Pf = fmaf(hv, tf, Pf); Pe = fmaf(hv, te, Pe);
    }
    S1 += __shfl_xor(S1, 32); S2 += __shfl_xor(S2, 32);
    Pf += __shfl_xor(Pf, 32); Pe += __shfl_xor(Pe, 32);
    if (dp == 0) {
        red[w][0][tq] = S1; red[w][1][tq] = S2; red[w][2][tq] = Pf; red[w][3][tq] = Pe;
    }
    __syncthreads();
    if (tid < 32) {
        float a[4];
#pragma unroll
        for (int k = 0; k < 4; k++)
            a[k] = red[0][k][tid] + red[1][k][tid] + red[2][k][tid] + red[3][k][tid];
        float mu  = a[0] * (1.f / 512.f);
        float var = a[1] * (1.f / 512.f) - mu * mu;
        float r   = rsqrtf(var + 1e-5f);
        float f0  = r * (a[2] - mu * P[PS2 + 0]) + P[PS2 + 2] + P[PSC + 0];
        float en  = r * (a[3] - mu * P[PS2 + 1]) + P[PS2 + 3] + P[PSC + 1];
        int tg2 = blockIdx.x * 32 + tid;
        if (f) {
            ((float*)out)[tg2]           = f0;
            ((float*)out)[B_ * T_ + tg2] = en;
        } else {
            ((unsigned short*)out)[tg2]           = f2us(f0);
            ((unsigned short*)out)[B_ * T_ + tg2] = f2us(en);
        }
    }
}

extern "C" void kernel_launch(void* const* d_in, const int* in_sizes, int n_in,
                              void* d_out, int out_size, void* d_ws, size_t ws_size,
                              hipStream_t stream) {
    (void)in_sizes; (void)n_in; (void)out_size; (void)ws_size;
    float* ws = (float*)d_ws;
    float* P     = ws;                                      // 106,528 slots (106,502 used)
    float* H     = ws + 106528;                             // 4,194,304
    unsigned short* textc = (unsigned short*)(ws + 4300832);// 4,194,304 bf16 (2,097,152 slots)
    unsigned short* Wt    = (unsigned short*)(ws + 6397984);// 262,144 bf16 (131,072 slots)
    float* P2    = ws + 6529056;                            // L*D*32 = 65,536 floats
    float* PW    = ws + 6594592;                            // L*D*64*16 = 2,097,152 floats (M=Ab^16 powers)
    // total: 8,691,744 floats = 34.8 MB

    prep_kernel<<<dim3(NB_TEXT + NB_PRM + NB_WT + NB_S4P + 1), dim3(256), 0, stream>>>(
        d_in[0], d_in[1], d_in[4], d_in[5], d_in[6], d_in[7], d_in[8],
        d_in[9], d_in[10], d_in[11], d_in[13], d_in[14], d_in[15],
        d_in[12], d_in[16], textc, Wt, P, P2, PW);
    gemm_kernel<<<dim3(8, 32, 4), dim3(256), 0, stream>>>(textc, Wt, d_in[3], d_in[2], d_in[9], H);
    s4_kernel<<<dim3(512), dim3(256), 0, stream>>>(H, P, P2, PW);
    final_kernel<<<dim3(256), dim3(256), 0, stream>>>(H, P, d_out, d_in[9]);
}